// Round 5
// baseline (259.416 us; speedup 1.0000x reference)
//
#include <hip/hip_runtime.h>
#include <stdint.h>

#define FM_BATCH      16384
#define FM_NUM_DENSE  13
#define FM_NUM_FIELDS 26
#define FM_FIELD_SIZE 100000
#define FM_K          32
#define FM_FEAT_LEN   2600013   // 26*100000 + 13
#define FM_SG         4         // sample groups of 4096
#define FM_SPG        4096
#define FM_CHUNK      512       // floats per stage chunk
#define FM_NCHUNK     196       // ceil(100000/512)
#define FM_HALF_F     13        // fields per half

// ws layout (u32 units)
#define WS_KEYS   0                                          // [26][4][4096] u32 sorted (idx<<12|lb)
#define WS_BOUNDS (WS_KEYS + FM_NUM_FIELDS*FM_SG*FM_SPG)     // [26][4][256] u32 chunk lower-bounds
#define WS_WSUM   (WS_BOUNDS + FM_NUM_FIELDS*FM_SG*256)      // [26][4][4096] f32 per-field w values
#define WS_TP     (WS_WSUM + FM_NUM_FIELDS*FM_SG*FM_SPG)     // [2][32][16384] float2 (L,S) partials

typedef __attribute__((address_space(1))) const void GAS;
typedef __attribute__((address_space(3))) void LAS;
__device__ __forceinline__ void gl_lds16(const float* g, float* l) {
    // 64 lanes x 16B -> LDS at wave-uniform base + lane*16
    __builtin_amdgcn_global_load_lds((GAS*)g, (LAS*)l, 16, 0, 0);
}

// ---- Kernel 1: per (field, sg) bitonic sort + chunk bounds + monotone w gather ----
__global__ __launch_bounds__(1024) void fm_sort(
    const int* __restrict__ sparse, const float* __restrict__ w,
    unsigned* __restrict__ keys, unsigned* __restrict__ bounds,
    float* __restrict__ wsum)
{
    const int f  = blockIdx.x >> 2;
    const int sg = blockIdx.x & 3;
    __shared__ unsigned s[FM_SPG];   // 16 KB
    __shared__ float    wt[FM_SPG];  // 16 KB
    const int t = threadIdx.x;

    for (int i = t; i < FM_SPG; i += 1024) {
        const int b = sg * FM_SPG + i;
        s[i] = ((unsigned)sparse[b * FM_NUM_FIELDS + f] << 12) | (unsigned)i;
    }
    for (int len = 2; len <= FM_SPG; len <<= 1)
        for (int inc = len >> 1; inc > 0; inc >>= 1) {
            __syncthreads();
            for (int x = t; x < FM_SPG; x += 1024) {
                const int y = x ^ inc;
                if (y > x) {
                    const unsigned a = s[x], c = s[y];
                    const bool up = ((x & len) == 0);
                    if ((a > c) == up) { s[x] = c; s[y] = a; }
                }
            }
        }
    __syncthreads();

    // monotone w gather: wt[local_sample] = w[field offset + idx]
    const float* wf = w + FM_NUM_DENSE + f * FM_FIELD_SIZE;
    for (int i = t; i < FM_SPG; i += 1024) {
        const unsigned key = s[i];
        wt[key & (FM_SPG - 1)] = wf[key >> 12];
    }
    // chunk lower-bounds: first pos with idx >= c*512
    unsigned* bo = bounds + (f * FM_SG + sg) * 256;
    for (int c = t; c <= FM_NCHUNK; c += 1024) {
        const unsigned thr = (unsigned)(c * FM_CHUNK) << 12;
        int lo = 0, hi = FM_SPG;
        while (lo < hi) { const int mid = (lo + hi) >> 1; if (s[mid] < thr) lo = mid + 1; else hi = mid; }
        bo[c] = (unsigned)lo;
    }
    __syncthreads();
    unsigned* kd = keys + (f * FM_SG + sg) * FM_SPG;
    float*    wd = wsum + (f * FM_SG + sg) * FM_SPG;
    for (int i = t; i < FM_SPG; i += 1024) { kd[i] = s[i]; wd[i] = wt[i]; }
}

// ---- Kernel 2: stream V slices through LDS, scatter-accumulate (L,S) ----
// block = (k, half, sg); bid%8 == k%8 pins the 4 sg-sharers of (k,half) to one XCD.
__global__ __launch_bounds__(1024) void fm_main(
    const float* __restrict__ dense, const float* __restrict__ V,
    const unsigned* __restrict__ keys, const unsigned* __restrict__ bounds,
    float2* __restrict__ tp)
{
    const int bid  = blockIdx.x;
    const int k    = bid & 31;
    const int half = (bid >> 5) & 1;
    const int sg   = bid >> 6;
    __shared__ float2 acc[FM_SPG];          // 32 KB
    __shared__ float  stage[16][FM_CHUNK];  // 32 KB
    const int t = threadIdx.x;
    const int wid = t >> 6, lane = t & 63;
    const float* Vk = V + (size_t)k * FM_FEAT_LEN;

    // acc init: half 0 carries the dense contribution, half 1 zeros
    for (int i = t; i < FM_SPG; i += 1024) {
        float aL = 0.f, aS = 0.f;
        if (half == 0) {
            const float* db = dense + (size_t)(sg * FM_SPG + i) * FM_NUM_DENSE;
            #pragma unroll
            for (int d = 0; d < FM_NUM_DENSE; ++d) {
                const float x = db[d], v = Vk[d];
                aL += x * v;
                aS += (x * x) * (v * v);
            }
        }
        acc[i] = make_float2(aL, aS);
    }
    __syncthreads();

    for (int ff = 0; ff < FM_HALF_F; ++ff) {
        const int f = half * FM_HALF_F + ff;
        const float* Vf = Vk + FM_NUM_DENSE + (size_t)f * FM_FIELD_SIZE;
        const unsigned* kf = keys   + (f * FM_SG + sg) * FM_SPG;
        const unsigned* bf = bounds + (f * FM_SG + sg) * 256;
        float* st = stage[wid];
        for (int c = wid; c < FM_NCHUNK; c += 16) {
            // prior chunk's LDS reads must retire before overwriting stage
            asm volatile("s_waitcnt lgkmcnt(0)" ::: "memory");
            const float* gb = Vf + c * FM_CHUNK;
            if (c < FM_NCHUNK - 1) {
                gl_lds16(gb + lane * 4, st);
                gl_lds16(gb + 256 + lane * 4, st + 256);
            } else {
                // last chunk: only 160 floats valid (avoid OOB past V row end)
                if (lane * 16 < 160 * 4) gl_lds16(gb + lane * 4, st);
            }
            const unsigned lo = bf[c], hi = bf[c + 1];
            asm volatile("s_waitcnt vmcnt(0)" ::: "memory");
            for (unsigned i = lo + lane; i < hi; i += 64) {
                const unsigned key = kf[i];
                const unsigned idx = key >> 12;
                const unsigned lb  = key & (FM_SPG - 1);
                const float v = st[idx - c * FM_CHUNK];
                float2 a = acc[lb];       // race-free: lb unique per field per block
                a.x += v;
                a.y += v * v;
                acc[lb] = a;
            }
        }
        __syncthreads();   // same lb reappears next field
    }

    float2* tpd = tp + ((size_t)(half * FM_K + k)) * FM_BATCH + sg * FM_SPG;
    for (int i = t; i < FM_SPG; i += 1024) tpd[i] = acc[i];
}

// ---- Kernel 3: combine halves, first-order, sigmoid (pure streaming) ----
__global__ __launch_bounds__(256) void fm_finish(
    const float* __restrict__ dense, const float* __restrict__ w0,
    const float* __restrict__ w, const float* __restrict__ wsum,
    const float2* __restrict__ tp, float* __restrict__ out)
{
    const int b  = blockIdx.x * 256 + threadIdx.x;
    const int sg = b >> 12, lb = b & (FM_SPG - 1);
    float ts = 0.f;
    #pragma unroll
    for (int k = 0; k < FM_K; ++k) {
        const float2 a = tp[(size_t)k * FM_BATCH + b];            // half 0
        const float2 c = tp[(size_t)(FM_K + k) * FM_BATCH + b];   // half 1
        const float L = a.x + c.x, S = a.y + c.y;
        ts += L * L - S;
    }
    float first = w0[0];
    #pragma unroll
    for (int d = 0; d < FM_NUM_DENSE; ++d)
        first += dense[b * FM_NUM_DENSE + d] * w[d];
    #pragma unroll
    for (int f = 0; f < FM_NUM_FIELDS; ++f)
        first += wsum[(f * FM_SG + sg) * FM_SPG + lb];
    const float z = first + 0.5f * ts;
    out[b] = 1.f / (1.f + __expf(-z));
}

extern "C" void kernel_launch(void* const* d_in, const int* in_sizes, int n_in,
                              void* d_out, int out_size, void* d_ws, size_t ws_size,
                              hipStream_t stream) {
    const float* dense  = (const float*)d_in[0];
    const int*   sparse = (const int*)d_in[1];
    const float* w0     = (const float*)d_in[2];
    const float* w      = (const float*)d_in[3];
    const float* V      = (const float*)d_in[4];
    float* out = (float*)d_out;

    unsigned* keys   = (unsigned*)d_ws + WS_KEYS;
    unsigned* bounds = (unsigned*)d_ws + WS_BOUNDS;
    float*    wsum   = (float*)d_ws + WS_WSUM;
    float2*   tp     = (float2*)((unsigned*)d_ws + WS_TP);

    fm_sort<<<FM_NUM_FIELDS * FM_SG, 1024, 0, stream>>>(sparse, w, keys, bounds, wsum);
    fm_main<<<FM_SG * 2 * FM_K, 1024, 0, stream>>>(dense, V, keys, bounds, tp);
    fm_finish<<<FM_BATCH / 256, 256, 0, stream>>>(dense, w0, w, wsum, tp, out);
}

// Round 6
// 215.668 us; speedup vs baseline: 1.2028x; 1.2028x over previous
//
#include <hip/hip_runtime.h>
#include <stdint.h>

#define FM_BATCH      16384
#define FM_NUM_DENSE  13
#define FM_NUM_FIELDS 26
#define FM_FIELD_SIZE 100000
#define FM_K          32
#define FM_FEAT_LEN   2600013   // 26*100000 + 13
#define FM_SG         4         // sample groups of 4096
#define FM_SPG        4096
#define FM_CHUNK      512       // floats per stage chunk
#define FM_NCHUNK     196       // ceil(100000/512); last chunk has 160 floats
#define FM_HALF_F     13        // fields per half
#define FM_NWAVE      16
#define FM_BSTRIDE    256       // bounds stride per (f,sg)

// ws layout (u32 units)
#define WS_KEYS   0                                          // [26][4][4096] u32 sorted (idx<<12|lb)
#define WS_BOUNDS (WS_KEYS + FM_NUM_FIELDS*FM_SG*FM_SPG)     // [26][4][256] u32 chunk lower-bounds
#define WS_WSUM   (WS_BOUNDS + FM_NUM_FIELDS*FM_SG*FM_BSTRIDE) // [26][4][4096] f32 per-field w values
#define WS_TP     (WS_WSUM + FM_NUM_FIELDS*FM_SG*FM_SPG)     // [2][32][16384] float2 (L,S) partials

typedef __attribute__((address_space(1))) const void GAS;
typedef __attribute__((address_space(3))) void LAS;
__device__ __forceinline__ void gl_lds16(const float* g, float* l) {
    // 64 lanes x 16B -> LDS at wave-uniform base + lane*16
    __builtin_amdgcn_global_load_lds((GAS*)g, (LAS*)l, 16, 0, 0);
}

// ---- Kernel 1: per (field, sg) bitonic sort + chunk bounds + monotone w gather ----
__global__ __launch_bounds__(1024) void fm_sort(
    const int* __restrict__ sparse, const float* __restrict__ w,
    unsigned* __restrict__ keys, unsigned* __restrict__ bounds,
    float* __restrict__ wsum)
{
    const int f  = blockIdx.x >> 2;
    const int sg = blockIdx.x & 3;
    __shared__ unsigned s[FM_SPG];   // 16 KB
    __shared__ float    wt[FM_SPG];  // 16 KB
    const int t = threadIdx.x;

    for (int i = t; i < FM_SPG; i += 1024) {
        const int b = sg * FM_SPG + i;
        s[i] = ((unsigned)sparse[b * FM_NUM_FIELDS + f] << 12) | (unsigned)i;
    }
    for (int len = 2; len <= FM_SPG; len <<= 1)
        for (int inc = len >> 1; inc > 0; inc >>= 1) {
            __syncthreads();
            for (int x = t; x < FM_SPG; x += 1024) {
                const int y = x ^ inc;
                if (y > x) {
                    const unsigned a = s[x], c = s[y];
                    const bool up = ((x & len) == 0);
                    if ((a > c) == up) { s[x] = c; s[y] = a; }
                }
            }
        }
    __syncthreads();

    // monotone w gather: wt[local_sample] = w[field offset + idx]
    const float* wf = w + FM_NUM_DENSE + f * FM_FIELD_SIZE;
    for (int i = t; i < FM_SPG; i += 1024) {
        const unsigned key = s[i];
        wt[key & (FM_SPG - 1)] = wf[key >> 12];
    }
    // chunk lower-bounds: first pos with idx >= c*512
    unsigned* bo = bounds + (f * FM_SG + sg) * FM_BSTRIDE;
    for (int c = t; c <= FM_NCHUNK; c += 1024) {
        const unsigned thr = (unsigned)(c * FM_CHUNK) << 12;
        int lo = 0, hi = FM_SPG;
        while (lo < hi) { const int mid = (lo + hi) >> 1; if (s[mid] < thr) lo = mid + 1; else hi = mid; }
        bo[c] = (unsigned)lo;
    }
    __syncthreads();
    unsigned* kd = keys + (f * FM_SG + sg) * FM_SPG;
    float*    wd = wsum + (f * FM_SG + sg) * FM_SPG;
    for (int i = t; i < FM_SPG; i += 1024) { kd[i] = s[i]; wd[i] = wt[i]; }
}

// ---- Kernel 2: stream V slices through LDS with a counted-vmcnt per-wave
// pipeline (depth 2, 3 buffers), scatter-accumulate (L,S) from sorted keys.
// block = (k, half, sg); bid%8 == k%8 pins the 4 sg-sharers of (k,half) to one XCD.
__global__ __launch_bounds__(1024) void fm_main(
    const float* __restrict__ dense, const float* __restrict__ V,
    const unsigned* __restrict__ keys, const unsigned* __restrict__ boundsg,
    float2* __restrict__ tp)
{
    const int bid  = blockIdx.x;
    const int k    = bid & 31;
    const int half = (bid >> 5) & 1;
    const int sg   = bid >> 6;

    __shared__ float2   acc[FM_SPG];                       // 32 KB
    __shared__ float    stage[FM_NWAVE][3][FM_CHUNK];      // 96 KB
    __shared__ unsigned blds[FM_HALF_F][FM_NCHUNK + 1];    // 10.2 KB

    const int t = threadIdx.x;
    const int wid = t >> 6, lane = t & 63;
    const float* Vk = V + (size_t)k * FM_FEAT_LEN;

    // bounds for this (half, sg) -> LDS (once; keeps counted loop clean)
    for (int i = t; i < FM_HALF_F * (FM_NCHUNK + 1); i += 1024) {
        const int ff = i / (FM_NCHUNK + 1), c = i % (FM_NCHUNK + 1);
        const int f = half * FM_HALF_F + ff;
        blds[ff][c] = boundsg[(f * FM_SG + sg) * FM_BSTRIDE + c];
    }

    // acc init: half 0 carries the dense contribution, half 1 zeros
    for (int i = t; i < FM_SPG; i += 1024) {
        float aL = 0.f, aS = 0.f;
        if (half == 0) {
            const float* db = dense + (size_t)(sg * FM_SPG + i) * FM_NUM_DENSE;
            #pragma unroll
            for (int d = 0; d < FM_NUM_DENSE; ++d) {
                const float x = db[d], v = Vk[d];
                aL += x * v;
                aS += (x * x) * (v * v);
            }
        }
        acc[i] = make_float2(aL, aS);
    }
    __syncthreads();

    const int nw = (FM_NCHUNK - wid + FM_NWAVE - 1) / FM_NWAVE;  // 12 or 13

    int iq = 0;   // issue rotation counter
    // issue chunk j of field ff into stage[wid][iq%3]
    auto issueF = [&](int ff, int j) {
        const int c = wid + j * FM_NWAVE;
        const int f = half * FM_HALF_F + ff;
        const float* gb = Vk + FM_NUM_DENSE + (size_t)f * FM_FIELD_SIZE + c * FM_CHUNK;
        float* st = stage[wid][iq % 3];
        const float* s1 = gb + lane * 4;
        const float* s2 = gb + 256 + lane * 4;
        if (c == FM_NCHUNK - 1) {       // only 160 floats valid; clamp in-row
            if (lane >= 40) s1 = gb;
            s2 = gb;
        }
        gl_lds16(s1, st);
        gl_lds16(s2, st + 256);
        ++iq;
    };

    issueF(0, 0);
    issueF(0, 1);
    int pq = 0;   // process rotation counter

    for (int ff = 0; ff < FM_HALF_F; ++ff) {
        const int f = half * FM_HALF_F + ff;
        const unsigned* kf = keys + (f * FM_SG + sg) * FM_SPG;

        for (int j = 0; j < nw; ++j) {
            const int a = j + 2;
            if (a < nw) {
                issueF(ff, a);
                asm volatile("s_waitcnt vmcnt(4)" ::: "memory");
            } else if (ff + 1 < FM_HALF_F) {
                issueF(ff + 1, a - nw);      // pre-issue next field across barrier
                asm volatile("s_waitcnt vmcnt(4)" ::: "memory");
            } else {
                asm volatile("s_waitcnt vmcnt(0)" ::: "memory");
            }

            const int c = wid + j * FM_NWAVE;
            const float* st = stage[wid][pq % 3];
            ++pq;
            const unsigned lo = blds[ff][c], hi = blds[ff][c + 1];
            const int base = c * FM_CHUNK;
            for (unsigned i = lo + lane; i < hi; i += 64) {
                const unsigned key = kf[i];
                const unsigned idx = key >> 12;
                const unsigned lb  = key & (FM_SPG - 1);
                const float v = st[idx - base];
                float2 aa = acc[lb];   // race-free: lb unique per field per block
                aa.x += v;
                aa.y += v * v;
                acc[lb] = aa;
            }
        }
        // cross-field barrier: LDS acc handoff needs lgkm only; keep the
        // pre-issued global_load_lds of the next field in flight (no vmcnt!)
        asm volatile("s_waitcnt lgkmcnt(0)" ::: "memory");
        __builtin_amdgcn_s_barrier();
    }

    float2* tpd = tp + ((size_t)(half * FM_K + k)) * FM_BATCH + sg * FM_SPG;
    for (int i = t; i < FM_SPG; i += 1024) tpd[i] = acc[i];
}

// ---- Kernel 3: combine halves, first-order, sigmoid (pure streaming) ----
__global__ __launch_bounds__(256) void fm_finish(
    const float* __restrict__ dense, const float* __restrict__ w0,
    const float* __restrict__ w, const float* __restrict__ wsum,
    const float2* __restrict__ tp, float* __restrict__ out)
{
    const int b  = blockIdx.x * 256 + threadIdx.x;
    const int sg = b >> 12, lb = b & (FM_SPG - 1);
    float ts = 0.f;
    #pragma unroll
    for (int k = 0; k < FM_K; ++k) {
        const float2 a = tp[(size_t)k * FM_BATCH + b];            // half 0
        const float2 c = tp[(size_t)(FM_K + k) * FM_BATCH + b];   // half 1
        const float L = a.x + c.x, S = a.y + c.y;
        ts += L * L - S;
    }
    float first = w0[0];
    #pragma unroll
    for (int d = 0; d < FM_NUM_DENSE; ++d)
        first += dense[b * FM_NUM_DENSE + d] * w[d];
    #pragma unroll
    for (int f = 0; f < FM_NUM_FIELDS; ++f)
        first += wsum[(f * FM_SG + sg) * FM_SPG + lb];
    const float z = first + 0.5f * ts;
    out[b] = 1.f / (1.f + __expf(-z));
}

extern "C" void kernel_launch(void* const* d_in, const int* in_sizes, int n_in,
                              void* d_out, int out_size, void* d_ws, size_t ws_size,
                              hipStream_t stream) {
    const float* dense  = (const float*)d_in[0];
    const int*   sparse = (const int*)d_in[1];
    const float* w0     = (const float*)d_in[2];
    const float* w      = (const float*)d_in[3];
    const float* V      = (const float*)d_in[4];
    float* out = (float*)d_out;

    unsigned* keys   = (unsigned*)d_ws + WS_KEYS;
    unsigned* bounds = (unsigned*)d_ws + WS_BOUNDS;
    float*    wsum   = (float*)d_ws + WS_WSUM;
    float2*   tp     = (float2*)((unsigned*)d_ws + WS_TP);

    fm_sort<<<FM_NUM_FIELDS * FM_SG, 1024, 0, stream>>>(sparse, w, keys, bounds, wsum);
    fm_main<<<FM_SG * 2 * FM_K, 1024, 0, stream>>>(dense, V, keys, bounds, tp);
    fm_finish<<<FM_BATCH / 256, 256, 0, stream>>>(dense, w0, w, wsum, tp, out);
}

// Round 7
// 165.166 us; speedup vs baseline: 1.5706x; 1.3058x over previous
//
#include <hip/hip_runtime.h>
#include <hip/hip_fp16.h>
#include <stdint.h>

#define FM_BATCH 16384
#define ND 13
#define NF 26
#define FS 100000
#define FL 2600013            // 26*100000 + 13
#define FL_PAD 2600192        // 10157 * 256 (grid-covered, padded)

// ---- Kernel 1: transpose + fp16-quantize V: [32][FL] f32 -> Vt [FL_PAD][32] fp16 ----
// Reads: per wave per k-row, 256 B contiguous (fully coalesced, 32 streams/block).
// Writes: each lane owns feature j -> its 64 B record is contiguous; 4 dwordx4
// stores per lane at stride 64 B across lanes; the wave fully covers 64 lines
// back-to-back so L2 write-back merges them into full-line HBM writes.
__global__ __launch_bounds__(256) void fm_prep(const float* __restrict__ V,
                                               unsigned* __restrict__ Vt)
{
    const int j = blockIdx.x * 256 + threadIdx.x;
    const bool in = (j < FL);
    unsigned pk[16];
#pragma unroll
    for (int r = 0; r < 16; ++r) {
        const float a = in ? __builtin_nontemporal_load(&V[(size_t)(2 * r) * FL + j]) : 0.f;
        const float b = in ? __builtin_nontemporal_load(&V[(size_t)(2 * r + 1) * FL + j]) : 0.f;
        const unsigned ha = __half_as_ushort(__float2half_rn(a));
        const unsigned hb = __half_as_ushort(__float2half_rn(b));
        pk[r] = ha | (hb << 16);
    }
    unsigned* dst = Vt + (size_t)j * 16;   // j < FL_PAD always: stores in-bounds
#pragma unroll
    for (int c = 0; c < 4; ++c) {
        *(uint4*)(dst + 4 * c) = make_uint4(pk[4 * c], pk[4 * c + 1],
                                            pk[4 * c + 2], pk[4 * c + 3]);
    }
}

// ---- Kernel 2: the whole FM. thread = (sample b, k-quarter q). ----
// Per (b,f): the 4 q-lanes load one dwordx4 each = the full 64 B Vt record,
// adjacent lanes -> coalesced. L/S accumulate in registers (8 k each);
// quad shfl_xor combines the 32-k second-order sum; q==0 writes sigmoid.
__global__ __launch_bounds__(256) void fm_gather(
    const float* __restrict__ dense,   // [BATCH][13]
    const int*   __restrict__ sparse,  // [BATCH][26]
    const float* __restrict__ w0,      // [1]
    const float* __restrict__ w,       // [FL]
    const uint4* __restrict__ Vt,      // [FL_PAD][4] uint4 (32 fp16)
    float* __restrict__ out)           // [BATCH]
{
    const int tid = blockIdx.x * 256 + threadIdx.x;
    const int b = tid >> 2;
    const int q = tid & 3;

    float L[8], S[8];
#pragma unroll
    for (int i = 0; i < 8; ++i) { L[i] = 0.f; S[i] = 0.f; }
    float first = 0.f;

    const float* __restrict__ db = dense + b * ND;
    const int*   __restrict__ sb = sparse + b * NF;

    // dense features: j = 0..12 (Vt records cache-hot)
#pragma unroll
    for (int d = 0; d < ND; ++d) {
        const float x = db[d];
        const uint4 r = Vt[(size_t)d * 4 + q];
        first += x * w[d];
        const __half2* h2 = reinterpret_cast<const __half2*>(&r);
#pragma unroll
        for (int i = 0; i < 4; ++i) {
            const float2 v = __half22float2(h2[i]);
            const float xa = x * v.x, xb = x * v.y;
            L[2 * i]     += xa;  S[2 * i]     += xa * xa;
            L[2 * i + 1] += xb;  S[2 * i + 1] += xb * xb;
        }
    }

    // sparse fields: one 64 B record per (b,f); fully unrolled -> 26 loads in flight
#pragma unroll
    for (int f = 0; f < NF; ++f) {
        const int idx = ND + f * FS + sb[f];
        const uint4 r = Vt[(size_t)idx * 4 + q];
        first += w[idx];   // same addr across the 4 q-lanes -> broadcast
        const __half2* h2 = reinterpret_cast<const __half2*>(&r);
#pragma unroll
        for (int i = 0; i < 4; ++i) {
            const float2 v = __half22float2(h2[i]);
            L[2 * i]     += v.x;  S[2 * i]     += v.x * v.x;
            L[2 * i + 1] += v.y;  S[2 * i + 1] += v.y * v.y;
        }
    }

    float t = 0.f;
#pragma unroll
    for (int i = 0; i < 8; ++i) t += L[i] * L[i] - S[i];
    t += __shfl_xor(t, 1);   // sum the 4 q-lanes of this sample
    t += __shfl_xor(t, 2);

    if (q == 0) {
        const float z = first + w0[0] + 0.5f * t;
        out[b] = 1.f / (1.f + __expf(-z));
    }
}

extern "C" void kernel_launch(void* const* d_in, const int* in_sizes, int n_in,
                              void* d_out, int out_size, void* d_ws, size_t ws_size,
                              hipStream_t stream) {
    const float* dense  = (const float*)d_in[0];
    const int*   sparse = (const int*)d_in[1];
    const float* w0     = (const float*)d_in[2];
    const float* w      = (const float*)d_in[3];
    const float* V      = (const float*)d_in[4];
    float* out = (float*)d_out;

    unsigned* Vt = (unsigned*)d_ws;   // FL_PAD * 64 B = 166.4 MB scratch

    fm_prep<<<FL_PAD / 256, 256, 0, stream>>>(V, Vt);
    fm_gather<<<(FM_BATCH * 4) / 256, 256, 0, stream>>>(
        dense, sparse, w0, w, (const uint4*)Vt, out);
}

// Round 8
// 114.435 us; speedup vs baseline: 2.2669x; 1.4433x over previous
//
#include <hip/hip_runtime.h>
#include <hip/hip_fp16.h>
#include <stdint.h>

#define FM_BATCH 16384
#define ND 13
#define NF 26
#define FS 100000
#define FL 2600013            // 26*100000 + 13
#define FL_PAD 2600192        // 10157 * 256

// ws layout: flags [FL_PAD] bytes (2.6 MB), then Vt [FL_PAD][16] u32 (166 MB)
#define N_FLAG4 (FL_PAD / 16)           // uint4 count for clear
#define N_MARK  (FM_BATCH * NF)         // 425984

// ---- Kernel 0: zero the flag array (must run every call: ws not re-poisoned,
// but we rebuild flags deterministically from inputs each call) ----
__global__ __launch_bounds__(256) void fm_clear(uint4* __restrict__ flags4)
{
    const int i = blockIdx.x * 256 + threadIdx.x;
    if (i < N_FLAG4) flags4[i] = make_uint4(0, 0, 0, 0);
}

// ---- Kernel 0b: mark referenced features (races write the same value 1) ----
__global__ __launch_bounds__(256) void fm_mark(const int* __restrict__ sparse,
                                               unsigned char* __restrict__ flags)
{
    const int t = blockIdx.x * 256 + threadIdx.x;   // t = b*26 + f, flat over sparse
    const int f = t % NF;
    flags[ND + f * FS + sparse[t]] = 1;
    if (t < ND) flags[t] = 1;                       // dense features always present
}

// ---- Kernel 1: transpose + fp16-quantize REFERENCED columns of V ----
// Reads stay coalesced (93% of 64B lines contain a flagged lane); writes drop
// from 166 MB to ~25 MB, leaving Vt L2/L3-resident for the gather.
__global__ __launch_bounds__(256) void fm_prep(const float* __restrict__ V,
                                               const unsigned char* __restrict__ flags,
                                               unsigned* __restrict__ Vt)
{
    const int j = blockIdx.x * 256 + threadIdx.x;
    if (j >= FL) return;
    if (!flags[j]) return;
    unsigned pk[16];
#pragma unroll
    for (int r = 0; r < 16; ++r) {
        const float a = __builtin_nontemporal_load(&V[(size_t)(2 * r) * FL + j]);
        const float b = __builtin_nontemporal_load(&V[(size_t)(2 * r + 1) * FL + j]);
        pk[r] = (unsigned)__half_as_ushort(__float2half_rn(a)) |
                ((unsigned)__half_as_ushort(__float2half_rn(b)) << 16);
    }
    unsigned* dst = Vt + (size_t)j * 16;
#pragma unroll
    for (int c = 0; c < 4; ++c)
        *(uint4*)(dst + 4 * c) = make_uint4(pk[4 * c], pk[4 * c + 1],
                                            pk[4 * c + 2], pk[4 * c + 3]);
}

// ---- Kernel 2: the whole FM. thread = (sample b, k-pair q), 16 lanes/sample.
// 1024 blocks -> 4 blocks/CU -> 4 waves/SIMD (4x the TLP of the R7 version).
__global__ __launch_bounds__(256) void fm_gather(
    const float* __restrict__ dense,   // [BATCH][13]
    const int*   __restrict__ sparse,  // [BATCH][26]
    const float* __restrict__ w0,      // [1]
    const float* __restrict__ w,       // [FL]
    const unsigned* __restrict__ Vt,   // [FL_PAD][16] u32 (32 fp16)
    float* __restrict__ out)           // [BATCH]
{
    const int tid = blockIdx.x * 256 + threadIdx.x;
    const int b = tid >> 4;
    const int q = tid & 15;            // half2 slot: ks {2q, 2q+1}

    float L0 = 0.f, L1 = 0.f, S0 = 0.f, S1 = 0.f, first = 0.f;
    const float* __restrict__ db = dense + b * ND;
    const int*   __restrict__ sb = sparse + b * NF;

#pragma unroll
    for (int d = 0; d < ND; ++d) {
        const float x = db[d];
        const unsigned r = Vt[(size_t)d * 16 + q];
        const float2 v = __half22float2(*(const __half2*)&r);
        first += x * w[d];
        const float a = x * v.x, c = x * v.y;
        L0 += a; S0 += a * a;
        L1 += c; S1 += c * c;
    }

    // 26 independent dword gathers in flight; 16 adjacent lanes = one 64B line
#pragma unroll
    for (int f = 0; f < NF; ++f) {
        const int idx = ND + f * FS + sb[f];
        const unsigned r = Vt[(size_t)idx * 16 + q];
        const float2 v = __half22float2(*(const __half2*)&r);
        first += w[idx];               // same addr across 16 lanes -> broadcast
        L0 += v.x; S0 += v.x * v.x;
        L1 += v.y; S1 += v.y * v.y;
    }

    float t = L0 * L0 - S0 + L1 * L1 - S1;
    t += __shfl_xor(t, 1);
    t += __shfl_xor(t, 2);
    t += __shfl_xor(t, 4);
    t += __shfl_xor(t, 8);             // sum over the 16 q-lanes

    if (q == 0) {
        const float z = first + w0[0] + 0.5f * t;
        out[b] = 1.f / (1.f + __expf(-z));
    }
}

extern "C" void kernel_launch(void* const* d_in, const int* in_sizes, int n_in,
                              void* d_out, int out_size, void* d_ws, size_t ws_size,
                              hipStream_t stream) {
    const float* dense  = (const float*)d_in[0];
    const int*   sparse = (const int*)d_in[1];
    const float* w0     = (const float*)d_in[2];
    const float* w      = (const float*)d_in[3];
    const float* V      = (const float*)d_in[4];
    float* out = (float*)d_out;

    unsigned char* flags = (unsigned char*)d_ws;            // 2.6 MB
    unsigned*      Vt    = (unsigned*)((char*)d_ws + FL_PAD); // 166 MB, 256B-aligned

    fm_clear<<<(N_FLAG4 + 255) / 256, 256, 0, stream>>>((uint4*)flags);
    fm_mark<<<N_MARK / 256, 256, 0, stream>>>(sparse, flags);
    fm_prep<<<FL_PAD / 256, 256, 0, stream>>>(V, flags, Vt);
    fm_gather<<<(FM_BATCH * 16) / 256, 256, 0, stream>>>(
        dense, sparse, w0, w, Vt, out);
}

// Round 9
// 111.574 us; speedup vs baseline: 2.3251x; 1.0256x over previous
//
#include <hip/hip_runtime.h>
#include <hip/hip_fp16.h>
#include <stdint.h>

#define FM_BATCH 16384
#define ND 13
#define NF 26
#define FS 100000
#define FL 2600013            // 26*100000 + 13
#define FL_PAD 2600192        // 10157 * 256

// ws layout: flags [FL_PAD] bytes (2.6 MB), then Vt [FL_PAD][16] u32 (166 MB)
#define N_MARK  (FM_BATCH * NF)         // 425984

// ---- Kernel 0: mark referenced features (races write the same value 1) ----
__global__ __launch_bounds__(256) void fm_mark(const int* __restrict__ sparse,
                                               unsigned char* __restrict__ flags)
{
    const int t = blockIdx.x * 256 + threadIdx.x;   // t = b*26 + f, flat over sparse
    const int f = t % NF;
    flags[ND + f * FS + sparse[t]] = 1;
    if (t < ND) flags[t] = 1;                       // dense features always present
}

// ---- Kernel 1: transpose + fp16-quantize REFERENCED columns of V ----
// Reads stay coalesced (93% of 64B lines contain a flagged lane); writes are
// ~27 MB, leaving Vt L2/L3-resident for the gather.
__global__ __launch_bounds__(256) void fm_prep(const float* __restrict__ V,
                                               const unsigned char* __restrict__ flags,
                                               unsigned* __restrict__ Vt)
{
    const int j = blockIdx.x * 256 + threadIdx.x;
    if (j >= FL) return;
    if (!flags[j]) return;
    unsigned pk[16];
#pragma unroll
    for (int r = 0; r < 16; ++r) {
        const float a = __builtin_nontemporal_load(&V[(size_t)(2 * r) * FL + j]);
        const float b = __builtin_nontemporal_load(&V[(size_t)(2 * r + 1) * FL + j]);
        pk[r] = (unsigned)__half_as_ushort(__float2half_rn(a)) |
                ((unsigned)__half_as_ushort(__float2half_rn(b)) << 16);
    }
    unsigned* dst = Vt + (size_t)j * 16;
#pragma unroll
    for (int c = 0; c < 4; ++c)
        *(uint4*)(dst + 4 * c) = make_uint4(pk[4 * c], pk[4 * c + 1],
                                            pk[4 * c + 2], pk[4 * c + 3]);
}

// ---- Kernel 2: the whole FM. 32 lanes/sample = 16 k-lanes x 2 field-halves.
// 2048 blocks -> 8 blocks/CU -> 32 waves/CU (max occupancy); ~13 scattered
// loads per lane whose latency is hidden by 8 waves/SIMD.
__global__ __launch_bounds__(256) void fm_gather(
    const float* __restrict__ dense,   // [BATCH][13]
    const int*   __restrict__ sparse,  // [BATCH][26]
    const float* __restrict__ w0,      // [1]
    const float* __restrict__ w,       // [FL]
    const unsigned* __restrict__ Vt,   // [FL_PAD][16] u32 (32 fp16)
    float* __restrict__ out)           // [BATCH]
{
    const int tid = blockIdx.x * 256 + threadIdx.x;
    const int b = tid >> 5;            // sample
    const int lane32 = tid & 31;
    const int q = lane32 & 15;         // k-pair slot: ks {2q, 2q+1}
    const int h = lane32 >> 4;         // field half: 0 -> dense + fields 0..12, 1 -> fields 13..25

    float L0 = 0.f, L1 = 0.f, S0 = 0.f, S1 = 0.f, first = 0.f;
    const float* __restrict__ db = dense + b * ND;
    const int*   __restrict__ sb = sparse + b * NF;

    if (h == 0) {
        // dense features (Vt records + w cache-hot)
#pragma unroll
        for (int d = 0; d < ND; ++d) {
            const float x = db[d];
            const unsigned r = Vt[(size_t)d * 16 + q];
            const float2 v = __half22float2(*(const __half2*)&r);
            first += x * w[d];
            const float a = x * v.x, c = x * v.y;
            L0 += a; S0 += a * a;
            L1 += c; S1 += c * c;
        }
    }

    // 13 sparse fields per half; all loads independent -> in flight together
    const int f0 = h * 13;
#pragma unroll
    for (int ff = 0; ff < 13; ++ff) {
        const int f = f0 + ff;
        const int idx = ND + f * FS + sb[f];
        const unsigned r = Vt[(size_t)idx * 16 + q];
        const float2 v = __half22float2(*(const __half2*)&r);
        first += w[idx];               // same addr across the 16 q-lanes -> broadcast
        L0 += v.x; S0 += v.x * v.x;
        L1 += v.y; S1 += v.y * v.y;
    }

    // combine the two field-halves per k (xor 16 swaps halves)
    L0 += __shfl_xor(L0, 16);  S0 += __shfl_xor(S0, 16);
    L1 += __shfl_xor(L1, 16);  S1 += __shfl_xor(S1, 16);
    first += __shfl_xor(first, 16);

    float t = L0 * L0 - S0 + L1 * L1 - S1;
    t += __shfl_xor(t, 1);
    t += __shfl_xor(t, 2);
    t += __shfl_xor(t, 4);
    t += __shfl_xor(t, 8);             // sum over the 16 q-lanes

    if (lane32 == 0) {
        const float z = first + w0[0] + 0.5f * t;
        out[b] = 1.f / (1.f + __expf(-z));
    }
}

extern "C" void kernel_launch(void* const* d_in, const int* in_sizes, int n_in,
                              void* d_out, int out_size, void* d_ws, size_t ws_size,
                              hipStream_t stream) {
    const float* dense  = (const float*)d_in[0];
    const int*   sparse = (const int*)d_in[1];
    const float* w0     = (const float*)d_in[2];
    const float* w      = (const float*)d_in[3];
    const float* V      = (const float*)d_in[4];
    float* out = (float*)d_out;

    unsigned char* flags = (unsigned char*)d_ws;              // 2.6 MB
    unsigned*      Vt    = (unsigned*)((char*)d_ws + FL_PAD); // 166 MB, 256B-aligned

    hipMemsetAsync(flags, 0, FL_PAD, stream);                 // graph-capturable
    fm_mark<<<N_MARK / 256, 256, 0, stream>>>(sparse, flags);
    fm_prep<<<FL_PAD / 256, 256, 0, stream>>>(V, flags, Vt);
    fm_gather<<<(FM_BATCH * 32) / 256, 256, 0, stream>>>(
        dense, sparse, w0, w, Vt, out);
}

// Round 10
// 103.045 us; speedup vs baseline: 2.5175x; 1.0828x over previous
//
#include <hip/hip_runtime.h>
#include <hip/hip_fp16.h>
#include <stdint.h>

#define FM_BATCH 16384
#define ND 13
#define NF 26
#define FS 100000
#define FL 2600013            // 26*100000 + 13
#define FL_PAD 2600192        // 10157 * 256

// ws layout: flags [FL_PAD] bytes (2.6 MB), then Vt [FL_PAD][16] u32 (166 MB)
#define N_MARK  (FM_BATCH * NF)         // 425984

// ---- Kernel 0: mark referenced features (races write the same value 1) ----
__global__ __launch_bounds__(256) void fm_mark(const int* __restrict__ sparse,
                                               unsigned char* __restrict__ flags)
{
    const int t = blockIdx.x * 256 + threadIdx.x;   // t = b*26 + f, flat over sparse
    const int f = t % NF;
    flags[ND + f * FS + sparse[t]] = 1;
    if (t < ND) flags[t] = 1;                       // dense features always present
}

// ---- Kernel 1: transpose + fp16-quantize REFERENCED columns of V ----
// Reads are UNCONDITIONAL and full-wave coalesced (64 lanes x 4B = 256B per
// row per wave) with NO nontemporal hint: across graph replays ~half of V
// stays Infinity-Cache-resident, and normal loads harvest that. Only the
// cvt+store is flag-gated (~16% of columns -> ~27 MB writes).
__global__ __launch_bounds__(256) void fm_prep(const float* __restrict__ V,
                                               const unsigned char* __restrict__ flags,
                                               unsigned* __restrict__ Vt)
{
    const int j = blockIdx.x * 256 + threadIdx.x;
    const bool in = (j < FL);
    const bool fl = in && (flags[j] != 0);

    float va[32];
#pragma unroll
    for (int r = 0; r < 32; ++r)
        va[r] = in ? V[(size_t)r * FL + j] : 0.f;

    // keep the loads un-sunk: force all 32 values live regardless of fl
#pragma unroll
    for (int r = 0; r < 32; ++r)
        asm volatile("" :: "v"(va[r]));

    if (!fl) return;

    unsigned pk[16];
#pragma unroll
    for (int r = 0; r < 16; ++r)
        pk[r] = (unsigned)__half_as_ushort(__float2half_rn(va[2 * r])) |
                ((unsigned)__half_as_ushort(__float2half_rn(va[2 * r + 1])) << 16);

    unsigned* dst = Vt + (size_t)j * 16;
#pragma unroll
    for (int c = 0; c < 4; ++c)
        *(uint4*)(dst + 4 * c) = make_uint4(pk[4 * c], pk[4 * c + 1],
                                            pk[4 * c + 2], pk[4 * c + 3]);
}

// ---- Kernel 2: the whole FM. 32 lanes/sample = 16 k-lanes x 2 field-halves.
// 2048 blocks -> 32 waves/CU (max occupancy).
__global__ __launch_bounds__(256) void fm_gather(
    const float* __restrict__ dense,   // [BATCH][13]
    const int*   __restrict__ sparse,  // [BATCH][26]
    const float* __restrict__ w0,      // [1]
    const float* __restrict__ w,       // [FL]
    const unsigned* __restrict__ Vt,   // [FL_PAD][16] u32 (32 fp16)
    float* __restrict__ out)           // [BATCH]
{
    const int tid = blockIdx.x * 256 + threadIdx.x;
    const int b = tid >> 5;            // sample
    const int lane32 = tid & 31;
    const int q = lane32 & 15;         // k-pair slot: ks {2q, 2q+1}
    const int h = lane32 >> 4;         // field half

    float L0 = 0.f, L1 = 0.f, S0 = 0.f, S1 = 0.f, first = 0.f;
    const float* __restrict__ db = dense + b * ND;
    const int*   __restrict__ sb = sparse + b * NF;

    if (h == 0) {
        // dense features (Vt records + w cache-hot)
#pragma unroll
        for (int d = 0; d < ND; ++d) {
            const float x = db[d];
            const unsigned r = Vt[(size_t)d * 16 + q];
            const float2 v = __half22float2(*(const __half2*)&r);
            first += x * w[d];
            const float a = x * v.x, c = x * v.y;
            L0 += a; S0 += a * a;
            L1 += c; S1 += c * c;
        }
    }

    // 13 sparse fields per half; all loads independent -> in flight together
    const int f0 = h * 13;
#pragma unroll
    for (int ff = 0; ff < 13; ++ff) {
        const int f = f0 + ff;
        const int idx = ND + f * FS + sb[f];
        const unsigned r = Vt[(size_t)idx * 16 + q];
        const float2 v = __half22float2(*(const __half2*)&r);
        first += w[idx];               // same addr across the 16 q-lanes -> broadcast
        L0 += v.x; S0 += v.x * v.x;
        L1 += v.y; S1 += v.y * v.y;
    }

    // combine the two field-halves per k (xor 16 swaps halves)
    L0 += __shfl_xor(L0, 16);  S0 += __shfl_xor(S0, 16);
    L1 += __shfl_xor(L1, 16);  S1 += __shfl_xor(S1, 16);
    first += __shfl_xor(first, 16);

    float t = L0 * L0 - S0 + L1 * L1 - S1;
    t += __shfl_xor(t, 1);
    t += __shfl_xor(t, 2);
    t += __shfl_xor(t, 4);
    t += __shfl_xor(t, 8);             // sum over the 16 q-lanes

    if (lane32 == 0) {
        const float z = first + w0[0] + 0.5f * t;
        out[b] = 1.f / (1.f + __expf(-z));
    }
}

extern "C" void kernel_launch(void* const* d_in, const int* in_sizes, int n_in,
                              void* d_out, int out_size, void* d_ws, size_t ws_size,
                              hipStream_t stream) {
    const float* dense  = (const float*)d_in[0];
    const int*   sparse = (const int*)d_in[1];
    const float* w0     = (const float*)d_in[2];
    const float* w      = (const float*)d_in[3];
    const float* V      = (const float*)d_in[4];
    float* out = (float*)d_out;

    unsigned char* flags = (unsigned char*)d_ws;              // 2.6 MB
    unsigned*      Vt    = (unsigned*)((char*)d_ws + FL_PAD); // 166 MB, 256B-aligned

    hipMemsetAsync(flags, 0, FL_PAD, stream);                 // graph-capturable
    fm_mark<<<N_MARK / 256, 256, 0, stream>>>(sparse, flags);
    fm_prep<<<FL_PAD / 256, 256, 0, stream>>>(V, flags, Vt);
    fm_gather<<<(FM_BATCH * 32) / 256, 256, 0, stream>>>(
        dense, sparse, w0, w, Vt, out);
}

// Round 11
// 102.993 us; speedup vs baseline: 2.5188x; 1.0005x over previous
//
#include <hip/hip_runtime.h>
#include <hip/hip_fp16.h>
#include <stdint.h>

#define FM_BATCH 16384
#define ND 13
#define NF 26
#define FS 100000
#define FL 2600013            // 26*100000 + 13
#define FL_PAD 2600192        // 10157 * 256

// ws layout: flags [FL_PAD] bytes (2.6 MB), then Vt [FL_PAD][16] u32 (166 MB)
#define N_MARK  (FM_BATCH * NF)         // 425984

// ---- Kernel 0: mark referenced features (races write the same value 1) ----
__global__ __launch_bounds__(256) void fm_mark(const int* __restrict__ sparse,
                                               unsigned char* __restrict__ flags)
{
    const int t = blockIdx.x * 256 + threadIdx.x;   // t = b*26 + f, flat over sparse
    const int f = t % NF;
    flags[ND + f * FS + sparse[t]] = 1;
    if (t < ND) flags[t] = 1;                       // dense features always present
}

// ---- Kernel 1: transpose + fp16-quantize referenced columns of V ----
// Reads: unconditional, full-wave coalesced (256 B/row/wave), no nt hint
// (L3 residency across replays is valuable).
// Writes: gated at 128 B LINE-PAIR granularity — thread j stores its 64 B
// record if EITHER j or j^1 is flagged, so both halves of every touched TCC
// line are written by adjacent lanes of the same wave -> full-line dirty,
// no partial-line read-allocate RMW from HBM.
__global__ __launch_bounds__(256) void fm_prep(const float* __restrict__ V,
                                               const unsigned char* __restrict__ flags,
                                               unsigned* __restrict__ Vt)
{
    const int j = blockIdx.x * 256 + threadIdx.x;
    const bool in = (j < FL);

    // pair flags: one aligned 2-byte load covers {j&~1, j|1}
    const unsigned short pf =
        *reinterpret_cast<const unsigned short*>(flags + (j & ~1));
    const bool fl = in && (pf != 0);

    float va[32];
#pragma unroll
    for (int r = 0; r < 32; ++r)
        va[r] = in ? V[(size_t)r * FL + j] : 0.f;

    // keep the loads un-sunk: force all 32 values live regardless of fl
#pragma unroll
    for (int r = 0; r < 32; ++r)
        asm volatile("" :: "v"(va[r]));

    if (!fl) return;

    unsigned pk[16];
#pragma unroll
    for (int r = 0; r < 16; ++r)
        pk[r] = (unsigned)__half_as_ushort(__float2half_rn(va[2 * r])) |
                ((unsigned)__half_as_ushort(__float2half_rn(va[2 * r + 1])) << 16);

    unsigned* dst = Vt + (size_t)j * 16;
#pragma unroll
    for (int c = 0; c < 4; ++c)
        *(uint4*)(dst + 4 * c) = make_uint4(pk[4 * c], pk[4 * c + 1],
                                            pk[4 * c + 2], pk[4 * c + 3]);
}

// ---- Kernel 2: the whole FM. 32 lanes/sample = 16 k-lanes x 2 field-halves.
// 2048 blocks -> 32 waves/CU (max occupancy).
__global__ __launch_bounds__(256) void fm_gather(
    const float* __restrict__ dense,   // [BATCH][13]
    const int*   __restrict__ sparse,  // [BATCH][26]
    const float* __restrict__ w0,      // [1]
    const float* __restrict__ w,       // [FL]
    const unsigned* __restrict__ Vt,   // [FL_PAD][16] u32 (32 fp16)
    float* __restrict__ out)           // [BATCH]
{
    const int tid = blockIdx.x * 256 + threadIdx.x;
    const int b = tid >> 5;            // sample
    const int lane32 = tid & 31;
    const int q = lane32 & 15;         // k-pair slot: ks {2q, 2q+1}
    const int h = lane32 >> 4;         // field half

    float L0 = 0.f, L1 = 0.f, S0 = 0.f, S1 = 0.f, first = 0.f;
    const float* __restrict__ db = dense + b * ND;
    const int*   __restrict__ sb = sparse + b * NF;

    if (h == 0) {
        // dense features (Vt records + w cache-hot)
#pragma unroll
        for (int d = 0; d < ND; ++d) {
            const float x = db[d];
            const unsigned r = Vt[(size_t)d * 16 + q];
            const float2 v = __half22float2(*(const __half2*)&r);
            first += x * w[d];
            const float a = x * v.x, c = x * v.y;
            L0 += a; S0 += a * a;
            L1 += c; S1 += c * c;
        }
    }

    // 13 sparse fields per half; all loads independent -> in flight together
    const int f0 = h * 13;
#pragma unroll
    for (int ff = 0; ff < 13; ++ff) {
        const int f = f0 + ff;
        const int idx = ND + f * FS + sb[f];
        const unsigned r = Vt[(size_t)idx * 16 + q];
        const float2 v = __half22float2(*(const __half2*)&r);
        first += w[idx];               // same addr across the 16 q-lanes -> broadcast
        L0 += v.x; S0 += v.x * v.x;
        L1 += v.y; S1 += v.y * v.y;
    }

    // combine the two field-halves per k (xor 16 swaps halves)
    L0 += __shfl_xor(L0, 16);  S0 += __shfl_xor(S0, 16);
    L1 += __shfl_xor(L1, 16);  S1 += __shfl_xor(S1, 16);
    first += __shfl_xor(first, 16);

    float t = L0 * L0 - S0 + L1 * L1 - S1;
    t += __shfl_xor(t, 1);
    t += __shfl_xor(t, 2);
    t += __shfl_xor(t, 4);
    t += __shfl_xor(t, 8);             // sum over the 16 q-lanes

    if (lane32 == 0) {
        const float z = first + w0[0] + 0.5f * t;
        out[b] = 1.f / (1.f + __expf(-z));
    }
}

extern "C" void kernel_launch(void* const* d_in, const int* in_sizes, int n_in,
                              void* d_out, int out_size, void* d_ws, size_t ws_size,
                              hipStream_t stream) {
    const float* dense  = (const float*)d_in[0];
    const int*   sparse = (const int*)d_in[1];
    const float* w0     = (const float*)d_in[2];
    const float* w      = (const float*)d_in[3];
    const float* V      = (const float*)d_in[4];
    float* out = (float*)d_out;

    unsigned char* flags = (unsigned char*)d_ws;              // 2.6 MB
    unsigned*      Vt    = (unsigned*)((char*)d_ws + FL_PAD); // 166 MB, 256B-aligned

    hipMemsetAsync(flags, 0, FL_PAD, stream);                 // graph-capturable
    fm_mark<<<N_MARK / 256, 256, 0, stream>>>(sparse, flags);
    fm_prep<<<FL_PAD / 256, 256, 0, stream>>>(V, flags, Vt);
    fm_gather<<<(FM_BATCH * 32) / 256, 256, 0, stream>>>(
        dense, sparse, w0, w, Vt, out);
}